// Round 2
// baseline (253.813 us; speedup 1.0000x reference)
//
#include <hip/hip_runtime.h>
#include <cstdint>
#include <cstddef>

// B=8, C=256, N=1024, T=60
// seq [B][C][N][T] fp32 (503 MB), out [B][T][T] fp32
//
// ws layout (float offsets):
//   f1p : [8 cg][B][60][1024] partials over c-groups  -> 3,932,160
//   f2p : [B][C][64 chunks][60] partials over n       -> 7,864,320  @  3,932,160
//   f2  : [B][C][60]                                  ->   122,880  @ 11,796,480
//   f1s : [B][60][1024]                               ->   491,520  @ 11,919,360
//   g1  : [B][60][C]                                  ->   122,880  @ 12,410,880
//   logits: [B][60][60]                               ->    28,800  @ 12,533,760
//   l2  : [B][60][60]                                 ->    28,800  @ 12,562,560
// total 12,591,360 floats = 50.4 MB (ws is ~2 GB per harness fills)

#define CSTRIDE 61440  // 1024*60 floats per c-plane

// ---------------------------------------------------------------------------
// Kernel A: single pass over seq. Barrier-free, LDS-free.
// grid 1024 = b(8) x cg(8, 32 c's each) x nc(16, 64 n's each); block 256.
// Lane map: wave wv (4), q = lane>>4 (0..3), r = lane&15 (r<15 active, t-quad 4r).
// Thread n's: n = nc*64 + wv*16 + 4j + q, j=0..3.
// Load addr floats = plane + (base_n+q)*60 + j*240 + 4r -> per wave-instr 960 B contiguous.
// f1 accumulates in 16 registers over the 32-c loop (partial per cg).
// f2 per-c: in-register sum over j, then butterfly shfl_xor(16,32) over q -> per-wave
// partial (16 n's) stored to f2p chunk nc*4+wv. No syncthreads anywhere.
// ---------------------------------------------------------------------------
__global__ __launch_bounds__(256) void kA(const float* __restrict__ seq,
                                          const float* __restrict__ w1,
                                          const float* __restrict__ w2,
                                          float* __restrict__ f1p,
                                          float* __restrict__ f2p) {
    const int blk  = blockIdx.x;            // 1024
    const int b    = blk >> 7;              // 0..7
    const int cg   = (blk >> 4) & 7;        // 0..7
    const int nc   = blk & 15;              // 0..15
    const int tid  = threadIdx.x;
    const int wv   = tid >> 6;              // 0..3
    const int lane = tid & 63;
    const int q    = lane >> 4;             // 0..3
    const int r    = lane & 15;             // 0..15, r==15 inactive
    const bool act = (r < 15);
    const int base_n = (nc << 6) + (wv << 4);
    const int c0   = cg << 5;

    float w2v[4];
    #pragma unroll
    for (int j = 0; j < 4; ++j) w2v[j] = w2[base_n + 4 * j + q];

    const float* p = seq + (size_t)(b * 256 + c0) * CSTRIDE + (base_n + q) * 60 + 4 * r;

    float4 A0[4], A1[4];
    #pragma unroll
    for (int j = 0; j < 4; ++j) { A0[j] = make_float4(0.f,0.f,0.f,0.f); A1[j] = A0[j]; }
    if (act) {
        #pragma unroll
        for (int j = 0; j < 4; ++j) A0[j] = *(const float4*)(p + j * 240);
    }
    p += CSTRIDE;
    if (act) {
        #pragma unroll
        for (int j = 0; j < 4; ++j) A1[j] = *(const float4*)(p + j * 240);
    }
    p += CSTRIDE;

    float4 acc[4];
    #pragma unroll
    for (int j = 0; j < 4; ++j) acc[j] = make_float4(0.f,0.f,0.f,0.f);

    for (int i = 0; i < 32; ++i) {
        float4 cur[4];
        #pragma unroll
        for (int j = 0; j < 4; ++j) { cur[j] = A0[j]; A0[j] = A1[j]; }
        if (act && i < 30) {
            #pragma unroll
            for (int j = 0; j < 4; ++j) A1[j] = *(const float4*)(p + j * 240);
        }
        p += CSTRIDE;

        const float wc = w1[c0 + i];
        #pragma unroll
        for (int j = 0; j < 4; ++j) {
            acc[j].x += wc * cur[j].x;
            acc[j].y += wc * cur[j].y;
            acc[j].z += wc * cur[j].z;
            acc[j].w += wc * cur[j].w;
        }

        float4 f2v;
        f2v.x = w2v[0]*cur[0].x + w2v[1]*cur[1].x + w2v[2]*cur[2].x + w2v[3]*cur[3].x;
        f2v.y = w2v[0]*cur[0].y + w2v[1]*cur[1].y + w2v[2]*cur[2].y + w2v[3]*cur[3].y;
        f2v.z = w2v[0]*cur[0].z + w2v[1]*cur[1].z + w2v[2]*cur[2].z + w2v[3]*cur[3].z;
        f2v.w = w2v[0]*cur[0].w + w2v[1]*cur[1].w + w2v[2]*cur[2].w + w2v[3]*cur[3].w;
        // butterfly over q (lanes ^16, ^32): sum of 16 n's per (r, comp)
        f2v.x += __shfl_xor(f2v.x, 16); f2v.x += __shfl_xor(f2v.x, 32);
        f2v.y += __shfl_xor(f2v.y, 16); f2v.y += __shfl_xor(f2v.y, 32);
        f2v.z += __shfl_xor(f2v.z, 16); f2v.z += __shfl_xor(f2v.z, 32);
        f2v.w += __shfl_xor(f2v.w, 16); f2v.w += __shfl_xor(f2v.w, 32);
        if (act && q == 0) {
            *(float4*)(f2p + ((size_t)(b * 256 + c0 + i) * 64 + nc * 4 + wv) * 60 + 4 * r) = f2v;
        }
    }

    if (act) {
        float* dst = f1p + ((size_t)((cg * 8 + b) * 60 + 4 * r)) * 1024 + base_n + q;
        #pragma unroll
        for (int j = 0; j < 4; ++j) {
            dst[0 * 1024 + 4 * j] = acc[j].x;
            dst[1 * 1024 + 4 * j] = acc[j].y;
            dst[2 * 1024 + 4 * j] = acc[j].z;
            dst[3 * 1024 + 4 * j] = acc[j].w;
        }
    }
}

// ---------------------------------------------------------------------------
// Kernel R: fused reductions. blocks [0,2048): f2 = sum of 64 chunks.
//           blocks [2048,2528): f1s row = sum of 8 cg partials.
// block 64.
// ---------------------------------------------------------------------------
__global__ __launch_bounds__(64) void kR(const float* __restrict__ f2p,
                                         const float* __restrict__ f1p,
                                         float* __restrict__ f2,
                                         float* __restrict__ f1s) {
    const int blk = blockIdx.x;
    const int tid = threadIdx.x;
    if (blk < 2048) {
        if (tid >= 60) return;
        const float* src = f2p + (size_t)blk * 64 * 60 + tid;
        float s = 0.f;
        #pragma unroll 8
        for (int k = 0; k < 64; ++k) s += src[k * 60];
        f2[(size_t)blk * 60 + tid] = s;
    } else {
        const int idx = blk - 2048;               // b*60 + t
        #pragma unroll
        for (int k = 0; k < 4; ++k) {
            const int fo = 4 * (tid + 64 * k);    // float offset in row
            float4 s = make_float4(0.f,0.f,0.f,0.f);
            #pragma unroll
            for (int g = 0; g < 8; ++g) {
                const float4 v = *(const float4*)(f1p + ((size_t)(g * 480) + idx) * 1024 + fo);
                s.x += v.x; s.y += v.y; s.z += v.z; s.w += v.w;
            }
            *(float4*)(f1s + (size_t)idx * 1024 + fo) = s;
        }
    }
}

// ---------------------------------------------------------------------------
// Kernel C: g1[b,t,c] = sum_n f1s[b,t,n] * w[n,c]. grid 120 = b(8) x tg(15),
// block 256 (thread = c). f1s reads are uniform (scalar path); w coalesced.
// ---------------------------------------------------------------------------
__global__ __launch_bounds__(256) void kC(const float* __restrict__ f1s,
                                          const float* __restrict__ w,
                                          float* __restrict__ g1) {
    const int b  = blockIdx.x / 15;
    const int tg = blockIdx.x % 15;
    const int c  = threadIdx.x;
    const float* r0 = f1s + ((size_t)(b * 60) + tg * 4) * 1024;
    float a0 = 0.f, a1 = 0.f, a2 = 0.f, a3 = 0.f;
    for (int n4 = 0; n4 < 256; ++n4) {
        const float4 f0 = *(const float4*)(r0 + 4 * n4);
        const float4 f1v = *(const float4*)(r0 + 1024 + 4 * n4);
        const float4 f2v = *(const float4*)(r0 + 2048 + 4 * n4);
        const float4 f3v = *(const float4*)(r0 + 3072 + 4 * n4);
        const float* wp = w + (size_t)(4 * n4) * 256 + c;
        const float w0 = wp[0], w1v = wp[256], w2v = wp[512], w3v = wp[768];
        a0 += f0.x * w0 + f0.y * w1v + f0.z * w2v + f0.w * w3v;
        a1 += f1v.x * w0 + f1v.y * w1v + f1v.z * w2v + f1v.w * w3v;
        a2 += f2v.x * w0 + f2v.y * w1v + f2v.z * w2v + f2v.w * w3v;
        a3 += f3v.x * w0 + f3v.y * w1v + f3v.z * w2v + f3v.w * w3v;
    }
    float* dst = g1 + ((size_t)b * 60 + (size_t)(tg * 4)) * 256 + c;
    dst[0]   = a0;
    dst[256] = a1;
    dst[512] = a2;
    dst[768] = a3;
}

// ---------------------------------------------------------------------------
// Kernel D: logits[b,t,s] = sigmoid( sum_c g1[b,t,c]*f2[b,c,s] + bmat[t,s] )
// grid 480 = b*60+t ; block 64 (thread = s).
// ---------------------------------------------------------------------------
__global__ __launch_bounds__(64) void kD(const float* __restrict__ g1,
                                         const float* __restrict__ f2,
                                         const float* __restrict__ bmat,
                                         float* __restrict__ logits) {
    const int bt = blockIdx.x;
    const int b  = bt / 60;
    const int t  = bt % 60;
    const int s  = threadIdx.x;
    const int sc = (s < 60) ? s : 0;
    const float* g = g1 + (size_t)bt * 256;
    const float* f = f2 + (size_t)b * 256 * 60;
    float acc = 0.f;
    #pragma unroll 4
    for (int c = 0; c < 256; ++c) acc += g[c] * f[c * 60 + sc];
    if (s < 60) {
        const float x = acc + bmat[t * 60 + s];
        logits[(size_t)bt * 60 + s] = 1.f / (1.f + __expf(-x));
    }
}

// ---------------------------------------------------------------------------
// Kernel E: l2[b,i,t] = sum_j v[i,j] * logits[b,j,t]. grid 480, block 64.
// ---------------------------------------------------------------------------
__global__ __launch_bounds__(64) void kE(const float* __restrict__ v,
                                         const float* __restrict__ logits,
                                         float* __restrict__ l2) {
    const int bi = blockIdx.x;
    const int b  = bi / 60;
    const int i  = bi % 60;
    const int t  = threadIdx.x;
    const int tc = (t < 60) ? t : 0;
    const float* lb = logits + (size_t)b * 3600;
    float acc = 0.f;
    #pragma unroll 4
    for (int j = 0; j < 60; ++j) acc += v[i * 60 + j] * lb[j * 60 + tc];
    if (t < 60) l2[(size_t)bi * 60 + t] = acc;
}

// ---------------------------------------------------------------------------
// Kernel G: fused BN stats (redundant per block, L2-resident) + BN apply +
// window mask + softmax. grid 480, block 64.
// ---------------------------------------------------------------------------
__global__ __launch_bounds__(64) void kG(const float* __restrict__ l2,
                                         const float* __restrict__ gamma,
                                         const float* __restrict__ beta,
                                         float* __restrict__ out) {
    const int bi = blockIdx.x;
    const int i  = bi % 60;
    const int t  = threadIdx.x;

    float x = -3.0e38f;
    if (t < 60) {
        float s = 0.f, ss = 0.f;
        #pragma unroll 4
        for (int k = 0; k < 480; ++k) {
            const float vv = l2[(size_t)k * 60 + t];
            s  += vv;
            ss += vv * vv;
        }
        const float m    = s * (1.f / 480.f);
        const float var  = ss * (1.f / 480.f) - m * m;
        const float rstd = rsqrtf(var + 1e-5f);

        const float val = l2[(size_t)bi * 60 + t];
        const float y   = (val - m) * rstd * gamma[t] + beta[t];
        const int  br   = (i < 36) ? (i / 12) : 3;
        const int  lo   = (br < 3) ? br * 12 : 36;
        const int  hi   = (br < 3) ? lo + 12 : 60;
        const bool valid = (t >= lo) && (t < hi);
        x = valid ? y : (y - 1e13f);
    }
    float mx = x;
    #pragma unroll
    for (int o = 32; o > 0; o >>= 1) mx = fmaxf(mx, __shfl_xor(mx, o));
    float e = 0.f;
    if (t < 60) e = __expf(x - mx);
    float sm = e;
    #pragma unroll
    for (int o = 32; o > 0; o >>= 1) sm += __shfl_xor(sm, o);
    if (t < 60) out[(size_t)bi * 60 + t] = e / sm;
}

// ---------------------------------------------------------------------------
extern "C" void kernel_launch(void* const* d_in, const int* in_sizes, int n_in,
                              void* d_out, int out_size, void* d_ws, size_t ws_size,
                              hipStream_t stream) {
    const float* seq   = (const float*)d_in[0];
    const float* w1    = (const float*)d_in[1];
    const float* w2    = (const float*)d_in[2];
    const float* w     = (const float*)d_in[3];
    const float* bmat  = (const float*)d_in[4];
    const float* v     = (const float*)d_in[5];
    const float* gamma = (const float*)d_in[6];
    const float* beta  = (const float*)d_in[7];
    float* out = (float*)d_out;
    float* ws  = (float*)d_ws;

    float* f1p    = ws;                  // 3,932,160
    float* f2p    = ws + 3932160;        // 7,864,320
    float* f2     = ws + 11796480;       //   122,880
    float* f1s    = ws + 11919360;       //   491,520
    float* g1     = ws + 12410880;       //   122,880
    float* logits = ws + 12533760;       //    28,800
    float* l2     = ws + 12562560;       //    28,800

    kA<<<1024, 256, 0, stream>>>(seq, w1, w2, f1p, f2p);
    kR<<<2528, 64, 0, stream>>>(f2p, f1p, f2, f1s);
    kC<<<120, 256, 0, stream>>>(f1s, w, g1);
    kD<<<480, 64, 0, stream>>>(g1, f2, bmat, logits);
    kE<<<480, 64, 0, stream>>>(v, logits, l2);
    kG<<<480, 64, 0, stream>>>(l2, gamma, beta, out);
}

// Round 3
// 249.418 us; speedup vs baseline: 1.0176x; 1.0176x over previous
//
#include <hip/hip_runtime.h>
#include <cstdint>
#include <cstddef>

// B=8, C=256, N=1024, T=60
// seq [B][C][N][T] fp32 (503 MB), out [B][T][T] fp32
//
// ws layout (float offsets):
//   f1p : [8 cg][B][60][1024] partials over c-groups  -> 3,932,160
//   f2p : [B][C][64 chunks][60] partials over n       -> 7,864,320  @  3,932,160
//   f2  : [B][C][60]                                  ->   122,880  @ 11,796,480
//   f1s : [B][60][1024]                               ->   491,520  @ 11,919,360
//   g1  : [B][60][C]                                  ->   122,880  @ 12,410,880
//   logits: [B][60][60]                               ->    28,800  @ 12,533,760
//   l2  : [B][60][60]                                 ->    28,800  @ 12,562,560
//   stats: mean[60]@+0, rstd[60]@+64                  ->       128  @ 12,591,360

#define CSTRIDE 61440  // 1024*60 floats per c-plane

// ---------------------------------------------------------------------------
// Kernel A (UNCHANGED from R2 — attribution control): single pass over seq.
// ---------------------------------------------------------------------------
__global__ __launch_bounds__(256) void kA(const float* __restrict__ seq,
                                          const float* __restrict__ w1,
                                          const float* __restrict__ w2,
                                          float* __restrict__ f1p,
                                          float* __restrict__ f2p) {
    const int blk  = blockIdx.x;            // 1024
    const int b    = blk >> 7;              // 0..7
    const int cg   = (blk >> 4) & 7;        // 0..7
    const int nc   = blk & 15;              // 0..15
    const int tid  = threadIdx.x;
    const int wv   = tid >> 6;              // 0..3
    const int lane = tid & 63;
    const int q    = lane >> 4;             // 0..3
    const int r    = lane & 15;             // 0..15, r==15 inactive
    const bool act = (r < 15);
    const int base_n = (nc << 6) + (wv << 4);
    const int c0   = cg << 5;

    float w2v[4];
    #pragma unroll
    for (int j = 0; j < 4; ++j) w2v[j] = w2[base_n + 4 * j + q];

    const float* p = seq + (size_t)(b * 256 + c0) * CSTRIDE + (base_n + q) * 60 + 4 * r;

    float4 A0[4], A1[4];
    #pragma unroll
    for (int j = 0; j < 4; ++j) { A0[j] = make_float4(0.f,0.f,0.f,0.f); A1[j] = A0[j]; }
    if (act) {
        #pragma unroll
        for (int j = 0; j < 4; ++j) A0[j] = *(const float4*)(p + j * 240);
    }
    p += CSTRIDE;
    if (act) {
        #pragma unroll
        for (int j = 0; j < 4; ++j) A1[j] = *(const float4*)(p + j * 240);
    }
    p += CSTRIDE;

    float4 acc[4];
    #pragma unroll
    for (int j = 0; j < 4; ++j) acc[j] = make_float4(0.f,0.f,0.f,0.f);

    for (int i = 0; i < 32; ++i) {
        float4 cur[4];
        #pragma unroll
        for (int j = 0; j < 4; ++j) { cur[j] = A0[j]; A0[j] = A1[j]; }
        if (act && i < 30) {
            #pragma unroll
            for (int j = 0; j < 4; ++j) A1[j] = *(const float4*)(p + j * 240);
        }
        p += CSTRIDE;

        const float wc = w1[c0 + i];
        #pragma unroll
        for (int j = 0; j < 4; ++j) {
            acc[j].x += wc * cur[j].x;
            acc[j].y += wc * cur[j].y;
            acc[j].z += wc * cur[j].z;
            acc[j].w += wc * cur[j].w;
        }

        float4 f2v;
        f2v.x = w2v[0]*cur[0].x + w2v[1]*cur[1].x + w2v[2]*cur[2].x + w2v[3]*cur[3].x;
        f2v.y = w2v[0]*cur[0].y + w2v[1]*cur[1].y + w2v[2]*cur[2].y + w2v[3]*cur[3].y;
        f2v.z = w2v[0]*cur[0].z + w2v[1]*cur[1].z + w2v[2]*cur[2].z + w2v[3]*cur[3].z;
        f2v.w = w2v[0]*cur[0].w + w2v[1]*cur[1].w + w2v[2]*cur[2].w + w2v[3]*cur[3].w;
        f2v.x += __shfl_xor(f2v.x, 16); f2v.x += __shfl_xor(f2v.x, 32);
        f2v.y += __shfl_xor(f2v.y, 16); f2v.y += __shfl_xor(f2v.y, 32);
        f2v.z += __shfl_xor(f2v.z, 16); f2v.z += __shfl_xor(f2v.z, 32);
        f2v.w += __shfl_xor(f2v.w, 16); f2v.w += __shfl_xor(f2v.w, 32);
        if (act && q == 0) {
            *(float4*)(f2p + ((size_t)(b * 256 + c0 + i) * 64 + nc * 4 + wv) * 60 + 4 * r) = f2v;
        }
    }

    if (act) {
        float* dst = f1p + ((size_t)((cg * 8 + b) * 60 + 4 * r)) * 1024 + base_n + q;
        #pragma unroll
        for (int j = 0; j < 4; ++j) {
            dst[0 * 1024 + 4 * j] = acc[j].x;
            dst[1 * 1024 + 4 * j] = acc[j].y;
            dst[2 * 1024 + 4 * j] = acc[j].z;
            dst[3 * 1024 + 4 * j] = acc[j].w;
        }
    }
}

// ---------------------------------------------------------------------------
// Kernel R: merged reductions, block 256.
//   blocks [0,512): 4 (b,c) rows each -> f2 = sum of 64 chunks (indep loads).
//   blocks [512,992): one (b,t) row  -> f1s = sum of 8 cg partials (float4).
// ---------------------------------------------------------------------------
__global__ __launch_bounds__(256) void kR(const float* __restrict__ f2p,
                                          const float* __restrict__ f1p,
                                          float* __restrict__ f2,
                                          float* __restrict__ f1s) {
    const int blk = blockIdx.x;
    const int tid = threadIdx.x;
    if (blk < 512) {
        const int row = blk * 4 + (tid >> 6);   // (b*256+c)
        const int t   = tid & 63;
        if (t >= 60) return;
        const float* src = f2p + (size_t)row * 3840 + t;  // 64*60 per row
        float s = 0.f;
        #pragma unroll 16
        for (int k = 0; k < 64; ++k) s += src[k * 60];
        f2[(size_t)row * 60 + t] = s;
    } else {
        const int bt = blk - 512;               // b*60 + t
        const float* src = f1p + (size_t)bt * 1024 + 4 * tid;
        float4 s = make_float4(0.f,0.f,0.f,0.f);
        #pragma unroll
        for (int g = 0; g < 8; ++g) {
            const float4 v = *(const float4*)(src + (size_t)g * 480 * 1024);
            s.x += v.x; s.y += v.y; s.z += v.z; s.w += v.w;
        }
        *(float4*)(f1s + (size_t)bt * 1024 + 4 * tid) = s;
    }
}

// ---------------------------------------------------------------------------
// Kernel C: g1[b,t,c] = sum_n f1s[b,t,n]*w[n,c]. grid 240 = b(8) x tg(30),
// 2 t-rows per block sharing each w load; f1s rows staged in LDS (broadcast).
// ---------------------------------------------------------------------------
__global__ __launch_bounds__(256) void kC(const float* __restrict__ f1s,
                                          const float* __restrict__ w,
                                          float* __restrict__ g1) {
    const int b  = blockIdx.x / 30;
    const int tg = blockIdx.x % 30;
    const int c  = threadIdx.x;
    __shared__ float fl[2048];

    const float* rows = f1s + ((size_t)(b * 60) + tg * 2) * 1024;
    // stage 2 rows = 512 float4, 2 per thread, coalesced
    #pragma unroll
    for (int k = 0; k < 2; ++k) {
        const int idx = c + k * 256;
        *(float4*)(&fl[4 * idx]) = *(const float4*)(rows + 4 * idx);
    }
    __syncthreads();

    float a0 = 0.f, a1 = 0.f;
    #pragma unroll 4
    for (int n = 0; n < 1024; ++n) {
        const float wv = w[n * 256 + c];
        a0 += fl[n] * wv;
        a1 += fl[1024 + n] * wv;
    }
    float* dst = g1 + ((size_t)b * 60 + (size_t)(tg * 2)) * 256 + c;
    dst[0]   = a0;
    dst[256] = a1;
}

// ---------------------------------------------------------------------------
// Kernel D: logits[b,t,s] = sigmoid( sum_c g1[b,t,c]*f2[b,c,s] + bmat[t,s] ).
// grid 480 = b*60+t, block 256. f2[b] slab (61.4 KB) + g1 row staged in LDS;
// 4-way c-split, LDS partial reduce. All loads independent & coalesced.
// ---------------------------------------------------------------------------
__global__ __launch_bounds__(256) void kD(const float* __restrict__ g1,
                                          const float* __restrict__ f2,
                                          const float* __restrict__ bmat,
                                          float* __restrict__ logits) {
    const int bt = blockIdx.x;
    const int b  = bt / 60;
    const int t  = bt % 60;
    const int tid = threadIdx.x;
    const int cq = tid >> 6;       // 0..3
    const int s  = tid & 63;

    __shared__ float f2s[15364];   // 256*60 + pad
    __shared__ float g1r[256];
    __shared__ float red[256];

    // stage f2[b]: 15,360 floats = 15 float4 per thread, coalesced
    const float* fsrc = f2 + (size_t)b * 15360;
    #pragma unroll
    for (int k = 0; k < 15; ++k) {
        const int idx = tid + k * 256;
        *(float4*)(&f2s[4 * idx]) = *(const float4*)(fsrc + 4 * idx);
    }
    if (tid < 64) {
        *(float4*)(&g1r[4 * tid]) = *(const float4*)(g1 + (size_t)bt * 256 + 4 * tid);
    }
    __syncthreads();

    float acc = 0.f;
    #pragma unroll 8
    for (int cc = 0; cc < 64; ++cc) {
        const int c = cq * 64 + cc;
        acc += g1r[c] * f2s[c * 60 + s];
    }
    red[tid] = acc;
    __syncthreads();
    if (tid < 60) {
        const float x = red[tid] + red[64 + tid] + red[128 + tid] + red[192 + tid]
                      + bmat[t * 60 + tid];
        logits[(size_t)bt * 60 + tid] = 1.f / (1.f + __expf(-x));
    }
}

// ---------------------------------------------------------------------------
// Kernel E: l2[b,i,t] = sum_j v[i,j]*logits[b,j,t]. grid 480, block 256.
// logits[b] slab (14.4 KB) staged in LDS.
// ---------------------------------------------------------------------------
__global__ __launch_bounds__(256) void kE(const float* __restrict__ v,
                                          const float* __restrict__ logits,
                                          float* __restrict__ l2) {
    const int bi = blockIdx.x;
    const int b  = bi / 60;
    const int i  = bi % 60;
    const int tid = threadIdx.x;

    __shared__ float L[3600];
    const float* src = logits + (size_t)b * 3600;
    // 900 float4: 3 per thread + 1 extra for tid<132
    #pragma unroll
    for (int k = 0; k < 3; ++k) {
        const int idx = tid + k * 256;
        *(float4*)(&L[4 * idx]) = *(const float4*)(src + 4 * idx);
    }
    if (tid < 132) {
        const int idx = tid + 768;
        *(float4*)(&L[4 * idx]) = *(const float4*)(src + 4 * idx);
    }
    __syncthreads();

    if (tid < 60) {
        float acc = 0.f;
        #pragma unroll 4
        for (int j = 0; j < 60; ++j) acc += v[i * 60 + j] * L[j * 60 + tid];
        l2[(size_t)bi * 60 + tid] = acc;
    }
}

// ---------------------------------------------------------------------------
// Kernel F: BN stats per channel t. grid 60 (one per t), block 64:
// thread m sums elements m, m+64, ... (8 guarded) then shfl tree.
// ---------------------------------------------------------------------------
__global__ __launch_bounds__(64) void kF(const float* __restrict__ l2,
                                         float* __restrict__ stats) {
    const int t = blockIdx.x;
    const int k = threadIdx.x;
    float s = 0.f, ss = 0.f;
    #pragma unroll
    for (int m = 0; m < 8; ++m) {
        const int idx = k + 64 * m;
        if (idx < 480) {
            const float x = l2[(size_t)idx * 60 + t];
            s  += x;
            ss += x * x;
        }
    }
    #pragma unroll
    for (int o = 32; o > 0; o >>= 1) { s += __shfl_xor(s, o); ss += __shfl_xor(ss, o); }
    if (k == 0) {
        const float m   = s * (1.f / 480.f);
        const float var = ss * (1.f / 480.f) - m * m;
        stats[t]      = m;
        stats[64 + t] = rsqrtf(var + 1e-5f);
    }
}

// ---------------------------------------------------------------------------
// Kernel G: BN apply + window mask + softmax. grid 480, block 64.
// ---------------------------------------------------------------------------
__global__ __launch_bounds__(64) void kG(const float* __restrict__ l2,
                                         const float* __restrict__ stats,
                                         const float* __restrict__ gamma,
                                         const float* __restrict__ beta,
                                         float* __restrict__ out) {
    const int bi = blockIdx.x;
    const int i  = bi % 60;
    const int t  = threadIdx.x;

    float x = -3.0e38f;
    if (t < 60) {
        const float val = l2[(size_t)bi * 60 + t];
        const float y   = (val - stats[t]) * stats[64 + t] * gamma[t] + beta[t];
        const int  br   = (i < 36) ? (i / 12) : 3;
        const int  lo   = (br < 3) ? br * 12 : 36;
        const int  hi   = (br < 3) ? lo + 12 : 60;
        const bool valid = (t >= lo) && (t < hi);
        x = valid ? y : (y - 1e13f);
    }
    float mx = x;
    #pragma unroll
    for (int o = 32; o > 0; o >>= 1) mx = fmaxf(mx, __shfl_xor(mx, o));
    float e = 0.f;
    if (t < 60) e = __expf(x - mx);
    float sm = e;
    #pragma unroll
    for (int o = 32; o > 0; o >>= 1) sm += __shfl_xor(sm, o);
    if (t < 60) out[(size_t)bi * 60 + t] = e / sm;
}

// ---------------------------------------------------------------------------
extern "C" void kernel_launch(void* const* d_in, const int* in_sizes, int n_in,
                              void* d_out, int out_size, void* d_ws, size_t ws_size,
                              hipStream_t stream) {
    const float* seq   = (const float*)d_in[0];
    const float* w1    = (const float*)d_in[1];
    const float* w2    = (const float*)d_in[2];
    const float* w     = (const float*)d_in[3];
    const float* bmat  = (const float*)d_in[4];
    const float* v     = (const float*)d_in[5];
    const float* gamma = (const float*)d_in[6];
    const float* beta  = (const float*)d_in[7];
    float* out = (float*)d_out;
    float* ws  = (float*)d_ws;

    float* f1p    = ws;                  // 3,932,160
    float* f2p    = ws + 3932160;        // 7,864,320
    float* f2     = ws + 11796480;       //   122,880
    float* f1s    = ws + 11919360;       //   491,520
    float* g1     = ws + 12410880;       //   122,880
    float* logits = ws + 12533760;       //    28,800
    float* l2     = ws + 12562560;       //    28,800
    float* stats  = ws + 12591360;       //       128

    kA<<<1024, 256, 0, stream>>>(seq, w1, w2, f1p, f2p);
    kR<<<992, 256, 0, stream>>>(f2p, f1p, f2, f1s);
    kC<<<240, 256, 0, stream>>>(f1s, w, g1);
    kD<<<480, 256, 0, stream>>>(g1, f2, bmat, logits);
    kE<<<480, 256, 0, stream>>>(v, logits, l2);
    kF<<<60, 64, 0, stream>>>(l2, stats);
    kG<<<480, 64, 0, stream>>>(l2, stats, gamma, beta, out);
}

// Round 5
// 191.832 us; speedup vs baseline: 1.3231x; 1.3002x over previous
//
#include <hip/hip_runtime.h>
#include <cstdint>
#include <cstddef>

// B=8, C=256, N=1024, T=60
// seq [B][C][N][T] fp32 (503 MB), out [B][T][T] fp32
//
// ws layout (float offsets):
//   f1p : [8 cg][B][60][1024] partials over c-groups  -> 3,932,160
//   f2p : [B][C][64 chunks][60] partials over n       -> 7,864,320  @  3,932,160
//   f2  : [B][C][60]                                  ->   122,880  @ 11,796,480
//   f1s : [B][60][1024]                               ->   491,520  @ 11,919,360
//   g1  : [B][60][C]                                  ->   122,880  @ 12,410,880
//   logits: [B][60][60]                               ->    28,800  @ 12,533,760
//   l2  : [B][60][60]                                 ->    28,800  @ 12,562,560
//   stats: mean[60]@+0, rstd[60]@+64                  ->       128  @ 12,591,360

#define CSTRIDE 61440  // 1024*60 floats per c-plane

typedef float vfloat4 __attribute__((ext_vector_type(4)));  // native vector for nontemporal builtin

// ---------------------------------------------------------------------------
// Kernel A v3: 4-deep statically-named pipeline + nontemporal seq loads.
// grid 1024 = b(8) x cg(8, 32 c's) x nc(16, 64 n's); block 256.
// Same lane map / addressing / outputs as R2-R3 (tail frozen for attribution).
// ---------------------------------------------------------------------------
__global__ __launch_bounds__(256) void kA(const float* __restrict__ seq,
                                          const float* __restrict__ w1,
                                          const float* __restrict__ w2,
                                          float* __restrict__ f1p,
                                          float* __restrict__ f2p) {
    const int blk  = blockIdx.x;            // 1024
    const int b    = blk >> 7;              // 0..7
    const int cg   = (blk >> 4) & 7;        // 0..7
    const int nc   = blk & 15;              // 0..15
    const int tid  = threadIdx.x;
    const int wv   = tid >> 6;              // 0..3
    const int lane = tid & 63;
    const int q    = lane >> 4;             // 0..3
    const int r    = lane & 15;             // r==15 inactive
    const bool act = (r < 15);
    const int base_n = (nc << 6) + (wv << 4);
    const int c0   = cg << 5;

    float w2v[4];
    #pragma unroll
    for (int j = 0; j < 4; ++j) w2v[j] = w2[base_n + 4 * j + q];

    const size_t planeOff = (size_t)(b * 256 + c0) * CSTRIDE + (size_t)((base_n + q) * 60 + 4 * r);
    const float* p0 = seq + planeOff;
    const float* p1 = p0 + (size_t)CSTRIDE;
    const float* p2 = p0 + 2 * (size_t)CSTRIDE;
    const float* p3 = p0 + 3 * (size_t)CSTRIDE;

    vfloat4 P0[4], P1[4], P2[4], P3[4];
    #pragma unroll
    for (int j = 0; j < 4; ++j) {
        P0[j] = (vfloat4)(0.f);
        P1[j] = P0[j]; P2[j] = P0[j]; P3[j] = P0[j];
    }
    if (act) {
        #pragma unroll
        for (int j = 0; j < 4; ++j) P0[j] = __builtin_nontemporal_load((const vfloat4*)(p0 + j * 240));
        #pragma unroll
        for (int j = 0; j < 4; ++j) P1[j] = __builtin_nontemporal_load((const vfloat4*)(p1 + j * 240));
        #pragma unroll
        for (int j = 0; j < 4; ++j) P2[j] = __builtin_nontemporal_load((const vfloat4*)(p2 + j * 240));
        #pragma unroll
        for (int j = 0; j < 4; ++j) P3[j] = __builtin_nontemporal_load((const vfloat4*)(p3 + j * 240));
    }
    // pointers now target the reload planes (c + 4)
    p0 += 4 * (size_t)CSTRIDE;
    p1 += 4 * (size_t)CSTRIDE;
    p2 += 4 * (size_t)CSTRIDE;
    p3 += 4 * (size_t)CSTRIDE;

    vfloat4 acc[4];
    #pragma unroll
    for (int j = 0; j < 4; ++j) acc[j] = (vfloat4)(0.f);

    // One pipeline step: consume plane P (c index ci), issue its reload, emit f2.
#define KA_STEP(P, S, PP)                                                               \
    {                                                                                   \
        const int ci = c0 + (ii << 2) + (S);                                            \
        const float wc = w1[ci];                                                        \
        _Pragma("unroll")                                                               \
        for (int j = 0; j < 4; ++j) acc[j] += wc * P[j];                                \
        vfloat4 f2v = w2v[0]*P[0] + w2v[1]*P[1] + w2v[2]*P[2] + w2v[3]*P[3];            \
        if (pref) { /* reload issued before the shfl/store chain */                     \
            _Pragma("unroll")                                                           \
            for (int j = 0; j < 4; ++j)                                                 \
                P[j] = __builtin_nontemporal_load((const vfloat4*)((PP) + j * 240));    \
        }                                                                               \
        f2v.x += __shfl_xor(f2v.x, 16); f2v.x += __shfl_xor(f2v.x, 32);                 \
        f2v.y += __shfl_xor(f2v.y, 16); f2v.y += __shfl_xor(f2v.y, 32);                 \
        f2v.z += __shfl_xor(f2v.z, 16); f2v.z += __shfl_xor(f2v.z, 32);                 \
        f2v.w += __shfl_xor(f2v.w, 16); f2v.w += __shfl_xor(f2v.w, 32);                 \
        if (act && q == 0) {                                                            \
            *(vfloat4*)(f2p + ((size_t)(b * 256 + ci) * 64 + nc * 4 + wv) * 60 + 4 * r) = f2v; \
        }                                                                               \
    }

    for (int ii = 0; ii < 8; ++ii) {
        const bool pref = act && (ii < 7);
        KA_STEP(P0, 0, p0)
        KA_STEP(P1, 1, p1)
        KA_STEP(P2, 2, p2)
        KA_STEP(P3, 3, p3)
        p0 += 4 * (size_t)CSTRIDE;
        p1 += 4 * (size_t)CSTRIDE;
        p2 += 4 * (size_t)CSTRIDE;
        p3 += 4 * (size_t)CSTRIDE;
    }
#undef KA_STEP

    if (act) {
        float* dst = f1p + ((size_t)((cg * 8 + b) * 60 + 4 * r)) * 1024 + base_n + q;
        #pragma unroll
        for (int j = 0; j < 4; ++j) {
            dst[0 * 1024 + 4 * j] = acc[j].x;
            dst[1 * 1024 + 4 * j] = acc[j].y;
            dst[2 * 1024 + 4 * j] = acc[j].z;
            dst[3 * 1024 + 4 * j] = acc[j].w;
        }
    }
}

// ---------------------------------------------------------------------------
// Kernel R (FROZEN from R3): merged reductions, block 256.
// ---------------------------------------------------------------------------
__global__ __launch_bounds__(256) void kR(const float* __restrict__ f2p,
                                          const float* __restrict__ f1p,
                                          float* __restrict__ f2,
                                          float* __restrict__ f1s) {
    const int blk = blockIdx.x;
    const int tid = threadIdx.x;
    if (blk < 512) {
        const int row = blk * 4 + (tid >> 6);   // (b*256+c)
        const int t   = tid & 63;
        if (t >= 60) return;
        const float* src = f2p + (size_t)row * 3840 + t;
        float s = 0.f;
        #pragma unroll 16
        for (int k = 0; k < 64; ++k) s += src[k * 60];
        f2[(size_t)row * 60 + t] = s;
    } else {
        const int bt = blk - 512;               // b*60 + t
        const float* src = f1p + (size_t)bt * 1024 + 4 * tid;
        float4 s = make_float4(0.f,0.f,0.f,0.f);
        #pragma unroll
        for (int g = 0; g < 8; ++g) {
            const float4 v = *(const float4*)(src + (size_t)g * 480 * 1024);
            s.x += v.x; s.y += v.y; s.z += v.z; s.w += v.w;
        }
        *(float4*)(f1s + (size_t)bt * 1024 + 4 * tid) = s;
    }
}

// ---------------------------------------------------------------------------
// Kernel C (FROZEN from R3)
// ---------------------------------------------------------------------------
__global__ __launch_bounds__(256) void kC(const float* __restrict__ f1s,
                                          const float* __restrict__ w,
                                          float* __restrict__ g1) {
    const int b  = blockIdx.x / 30;
    const int tg = blockIdx.x % 30;
    const int c  = threadIdx.x;
    __shared__ float fl[2048];

    const float* rows = f1s + ((size_t)(b * 60) + tg * 2) * 1024;
    #pragma unroll
    for (int k = 0; k < 2; ++k) {
        const int idx = c + k * 256;
        *(float4*)(&fl[4 * idx]) = *(const float4*)(rows + 4 * idx);
    }
    __syncthreads();

    float a0 = 0.f, a1 = 0.f;
    #pragma unroll 4
    for (int n = 0; n < 1024; ++n) {
        const float wv = w[n * 256 + c];
        a0 += fl[n] * wv;
        a1 += fl[1024 + n] * wv;
    }
    float* dst = g1 + ((size_t)b * 60 + (size_t)(tg * 2)) * 256 + c;
    dst[0]   = a0;
    dst[256] = a1;
}

// ---------------------------------------------------------------------------
// Kernel D (FROZEN from R3)
// ---------------------------------------------------------------------------
__global__ __launch_bounds__(256) void kD(const float* __restrict__ g1,
                                          const float* __restrict__ f2,
                                          const float* __restrict__ bmat,
                                          float* __restrict__ logits) {
    const int bt = blockIdx.x;
    const int b  = bt / 60;
    const int t  = bt % 60;
    const int tid = threadIdx.x;
    const int cq = tid >> 6;
    const int s  = tid & 63;

    __shared__ float f2s[15364];
    __shared__ float g1r[256];
    __shared__ float red[256];

    const float* fsrc = f2 + (size_t)b * 15360;
    #pragma unroll
    for (int k = 0; k < 15; ++k) {
        const int idx = tid + k * 256;
        *(float4*)(&f2s[4 * idx]) = *(const float4*)(fsrc + 4 * idx);
    }
    if (tid < 64) {
        *(float4*)(&g1r[4 * tid]) = *(const float4*)(g1 + (size_t)bt * 256 + 4 * tid);
    }
    __syncthreads();

    float acc = 0.f;
    #pragma unroll 8
    for (int cc = 0; cc < 64; ++cc) {
        const int c = cq * 64 + cc;
        acc += g1r[c] * f2s[c * 60 + s];
    }
    red[tid] = acc;
    __syncthreads();
    if (tid < 60) {
        const float x = red[tid] + red[64 + tid] + red[128 + tid] + red[192 + tid]
                      + bmat[t * 60 + tid];
        logits[(size_t)bt * 60 + tid] = 1.f / (1.f + __expf(-x));
    }
}

// ---------------------------------------------------------------------------
// Kernel E (FROZEN from R3)
// ---------------------------------------------------------------------------
__global__ __launch_bounds__(256) void kE(const float* __restrict__ v,
                                          const float* __restrict__ logits,
                                          float* __restrict__ l2) {
    const int bi = blockIdx.x;
    const int b  = bi / 60;
    const int i  = bi % 60;
    const int tid = threadIdx.x;

    __shared__ float L[3600];
    const float* src = logits + (size_t)b * 3600;
    #pragma unroll
    for (int k = 0; k < 3; ++k) {
        const int idx = tid + k * 256;
        *(float4*)(&L[4 * idx]) = *(const float4*)(src + 4 * idx);
    }
    if (tid < 132) {
        const int idx = tid + 768;
        *(float4*)(&L[4 * idx]) = *(const float4*)(src + 4 * idx);
    }
    __syncthreads();

    if (tid < 60) {
        float acc = 0.f;
        #pragma unroll 4
        for (int j = 0; j < 60; ++j) acc += v[i * 60 + j] * L[j * 60 + tid];
        l2[(size_t)bi * 60 + tid] = acc;
    }
}

// ---------------------------------------------------------------------------
// Kernel F (FROZEN from R3)
// ---------------------------------------------------------------------------
__global__ __launch_bounds__(64) void kF(const float* __restrict__ l2,
                                         float* __restrict__ stats) {
    const int t = blockIdx.x;
    const int k = threadIdx.x;
    float s = 0.f, ss = 0.f;
    #pragma unroll
    for (int m = 0; m < 8; ++m) {
        const int idx = k + 64 * m;
        if (idx < 480) {
            const float x = l2[(size_t)idx * 60 + t];
            s  += x;
            ss += x * x;
        }
    }
    #pragma unroll
    for (int o = 32; o > 0; o >>= 1) { s += __shfl_xor(s, o); ss += __shfl_xor(ss, o); }
    if (k == 0) {
        const float m   = s * (1.f / 480.f);
        const float var = ss * (1.f / 480.f) - m * m;
        stats[t]      = m;
        stats[64 + t] = rsqrtf(var + 1e-5f);
    }
}

// ---------------------------------------------------------------------------
// Kernel G (FROZEN from R3)
// ---------------------------------------------------------------------------
__global__ __launch_bounds__(64) void kG(const float* __restrict__ l2,
                                         const float* __restrict__ stats,
                                         const float* __restrict__ gamma,
                                         const float* __restrict__ beta,
                                         float* __restrict__ out) {
    const int bi = blockIdx.x;
    const int i  = bi % 60;
    const int t  = threadIdx.x;

    float x = -3.0e38f;
    if (t < 60) {
        const float val = l2[(size_t)bi * 60 + t];
        const float y   = (val - stats[t]) * stats[64 + t] * gamma[t] + beta[t];
        const int  br   = (i < 36) ? (i / 12) : 3;
        const int  lo   = (br < 3) ? br * 12 : 36;
        const int  hi   = (br < 3) ? lo + 12 : 60;
        const bool valid = (t >= lo) && (t < hi);
        x = valid ? y : (y - 1e13f);
    }
    float mx = x;
    #pragma unroll
    for (int o = 32; o > 0; o >>= 1) mx = fmaxf(mx, __shfl_xor(mx, o));
    float e = 0.f;
    if (t < 60) e = __expf(x - mx);
    float sm = e;
    #pragma unroll
    for (int o = 32; o > 0; o >>= 1) sm += __shfl_xor(sm, o);
    if (t < 60) out[(size_t)bi * 60 + t] = e / sm;
}

// ---------------------------------------------------------------------------
extern "C" void kernel_launch(void* const* d_in, const int* in_sizes, int n_in,
                              void* d_out, int out_size, void* d_ws, size_t ws_size,
                              hipStream_t stream) {
    const float* seq   = (const float*)d_in[0];
    const float* w1    = (const float*)d_in[1];
    const float* w2    = (const float*)d_in[2];
    const float* w     = (const float*)d_in[3];
    const float* bmat  = (const float*)d_in[4];
    const float* v     = (const float*)d_in[5];
    const float* gamma = (const float*)d_in[6];
    const float* beta  = (const float*)d_in[7];
    float* out = (float*)d_out;
    float* ws  = (float*)d_ws;

    float* f1p    = ws;                  // 3,932,160
    float* f2p    = ws + 3932160;        // 7,864,320
    float* f2     = ws + 11796480;       //   122,880
    float* f1s    = ws + 11919360;       //   491,520
    float* g1     = ws + 12410880;       //   122,880
    float* logits = ws + 12533760;       //    28,800
    float* l2     = ws + 12562560;       //    28,800
    float* stats  = ws + 12591360;       //       128

    kA<<<1024, 256, 0, stream>>>(seq, w1, w2, f1p, f2p);
    kR<<<992, 256, 0, stream>>>(f2p, f1p, f2, f1s);
    kC<<<240, 256, 0, stream>>>(f1s, w, g1);
    kD<<<480, 256, 0, stream>>>(g1, f2, bmat, logits);
    kE<<<480, 256, 0, stream>>>(v, logits, l2);
    kF<<<60, 64, 0, stream>>>(l2, stats);
    kG<<<480, 64, 0, stream>>>(l2, stats, gamma, beta, out);
}

// Round 6
// 186.351 us; speedup vs baseline: 1.3620x; 1.0294x over previous
//
#include <hip/hip_runtime.h>
#include <cstdint>
#include <cstddef>

// B=8, C=256, N=1024, T=60
// seq [B][C][N][T] fp32 (503 MB), out [B][T][T] fp32
//
// ws layout (float offsets):
//   f1p : [8 cg][B][60][1024] partials over c-groups  -> 3,932,160
//   f2p : [B][C][64 chunks][60] partials over n       -> 7,864,320  @  3,932,160
//   f2  : [B][C][60]                                  ->   122,880  @ 11,796,480
//   f1s : [B][60][1024]                               ->   491,520  @ 11,919,360
//   g1  : [B][60][C]                                  ->   122,880  @ 12,410,880
//   logits: [B][60][60]                               ->    28,800  @ 12,533,760
//   l2  : [B][60][60]                                 ->    28,800  @ 12,562,560
//   stats: mean[60]@+0, rstd[60]@+64                  ->       128  @ 12,591,360

#define CSTRIDE 61440  // 1024*60 floats per c-plane

typedef float vfloat4 __attribute__((ext_vector_type(4)));

// quad-lane (xor1 + xor2) sum via DPP quad_perm — VALU only, no LDS pipe.
__device__ __forceinline__ float quad_reduce(float x) {
    int y1 = __builtin_amdgcn_update_dpp(0, __float_as_int(x), 0xB1, 0xF, 0xF, true);
    float s1 = x + __int_as_float(y1);
    int y2 = __builtin_amdgcn_update_dpp(0, __float_as_int(s1), 0x4E, 0xF, 0xF, true);
    return s1 + __int_as_float(y2);
}

// ---------------------------------------------------------------------------
// Kernel A v4: pure-load vmcnt domain. 4-deep NT pipeline; f2 partials
// quad-reduced via DPP and buffered in LDS; single coalesced flush at end.
// grid 1024 = b(8) x cg(8, 32 c's) x nc(16, 64 n's); block 256.
// Lane map: q = lane&3 (n-sub), r = lane>>2 (t-quad, r<15 active).
// Load addr floats = plane + (base_n+q)*60 + j*240 + 4r  -> 960 B/instr contiguous.
// ---------------------------------------------------------------------------
__global__ __launch_bounds__(256) void kA(const float* __restrict__ seq,
                                          const float* __restrict__ w1,
                                          const float* __restrict__ w2,
                                          float* __restrict__ f1p,
                                          float* __restrict__ f2p) {
    const int blk  = blockIdx.x;            // 1024
    const int b    = blk >> 7;              // 0..7
    const int cg   = (blk >> 4) & 7;        // 0..7
    const int nc   = blk & 15;              // 0..15
    const int tid  = threadIdx.x;
    const int wv   = tid >> 6;              // 0..3
    const int lane = tid & 63;
    const int q    = lane & 3;              // n-sub
    const int r    = lane >> 2;             // t-quad; r==15 inactive
    const bool act = (r < 15);
    const int base_n = (nc << 6) + (wv << 4);
    const int c0   = cg << 5;

    __shared__ float lf2[7680];             // [cc 32][wv 4][60]

    float w2v[4];
    #pragma unroll
    for (int j = 0; j < 4; ++j) w2v[j] = w2[base_n + 4 * j + q];

    const size_t planeOff = (size_t)(b * 256 + c0) * CSTRIDE + (size_t)((base_n + q) * 60 + 4 * r);
    const float* p0 = seq + planeOff;
    const float* p1 = p0 + (size_t)CSTRIDE;
    const float* p2 = p0 + 2 * (size_t)CSTRIDE;
    const float* p3 = p0 + 3 * (size_t)CSTRIDE;

    vfloat4 P0[4], P1[4], P2[4], P3[4];
    #pragma unroll
    for (int j = 0; j < 4; ++j) {
        P0[j] = (vfloat4)(0.f);
        P1[j] = P0[j]; P2[j] = P0[j]; P3[j] = P0[j];
    }
    if (act) {
        #pragma unroll
        for (int j = 0; j < 4; ++j) P0[j] = __builtin_nontemporal_load((const vfloat4*)(p0 + j * 240));
        #pragma unroll
        for (int j = 0; j < 4; ++j) P1[j] = __builtin_nontemporal_load((const vfloat4*)(p1 + j * 240));
        #pragma unroll
        for (int j = 0; j < 4; ++j) P2[j] = __builtin_nontemporal_load((const vfloat4*)(p2 + j * 240));
        #pragma unroll
        for (int j = 0; j < 4; ++j) P3[j] = __builtin_nontemporal_load((const vfloat4*)(p3 + j * 240));
    }
    p0 += 4 * (size_t)CSTRIDE;
    p1 += 4 * (size_t)CSTRIDE;
    p2 += 4 * (size_t)CSTRIDE;
    p3 += 4 * (size_t)CSTRIDE;

    vfloat4 acc[4];
    #pragma unroll
    for (int j = 0; j < 4; ++j) acc[j] = (vfloat4)(0.f);

    // Step: consume plane P (c-offset cc), issue reload, DPP-reduce f2, LDS-buffer.
#define KA_STEP(P, S, PP)                                                               \
    {                                                                                   \
        const int cc = (ii << 2) + (S);                                                 \
        const float wc = w1[c0 + cc];                                                   \
        _Pragma("unroll")                                                               \
        for (int j = 0; j < 4; ++j) acc[j] += wc * P[j];                                \
        vfloat4 f2v = w2v[0]*P[0] + w2v[1]*P[1] + w2v[2]*P[2] + w2v[3]*P[3];            \
        if (pref) {                                                                     \
            _Pragma("unroll")                                                           \
            for (int j = 0; j < 4; ++j)                                                 \
                P[j] = __builtin_nontemporal_load((const vfloat4*)((PP) + j * 240));    \
        }                                                                               \
        f2v.x = quad_reduce(f2v.x);                                                     \
        f2v.y = quad_reduce(f2v.y);                                                     \
        f2v.z = quad_reduce(f2v.z);                                                     \
        f2v.w = quad_reduce(f2v.w);                                                     \
        if (act && q == 0) {                                                            \
            *(vfloat4*)(&lf2[(cc * 4 + wv) * 60 + 4 * r]) = f2v;                        \
        }                                                                               \
    }

    for (int ii = 0; ii < 8; ++ii) {
        const bool pref = act && (ii < 7);
        KA_STEP(P0, 0, p0)
        KA_STEP(P1, 1, p1)
        KA_STEP(P2, 2, p2)
        KA_STEP(P3, 3, p3)
        p0 += 4 * (size_t)CSTRIDE;
        p1 += 4 * (size_t)CSTRIDE;
        p2 += 4 * (size_t)CSTRIDE;
        p3 += 4 * (size_t)CSTRIDE;
    }
#undef KA_STEP

    // f1 partial write (outside loop, off the pipeline's critical path)
    if (act) {
        float* dst = f1p + ((size_t)((cg * 8 + b) * 60 + 4 * r)) * 1024 + base_n + q;
        #pragma unroll
        for (int j = 0; j < 4; ++j) {
            dst[0 * 1024 + 4 * j] = acc[j].x;
            dst[1 * 1024 + 4 * j] = acc[j].y;
            dst[2 * 1024 + 4 * j] = acc[j].z;
            dst[3 * 1024 + 4 * j] = acc[j].w;
        }
    }

    // Flush LDS f2 buffer -> f2p (layout unchanged: [b][c][64 chunks][60]).
    __syncthreads();
    float* f2base = f2p + ((size_t)(b * 256 + c0) * 64 + nc * 4) * 60;
    #pragma unroll
    for (int k = 0; k < 8; ++k) {
        const int idx = k * 256 + tid;      // float4 index, 1920 total
        if (idx < 1920) {
            const int row = idx / 15;       // cc*4 + wv
            const int p   = idx - row * 15;
            const vfloat4 v = *(const vfloat4*)(&lf2[row * 60 + 4 * p]);
            *(vfloat4*)(f2base + (size_t)(row >> 2) * 3840 + (row & 3) * 60 + 4 * p) = v;
        }
    }
}

// ---------------------------------------------------------------------------
// Kernel R (FROZEN from R3): merged reductions, block 256.
// ---------------------------------------------------------------------------
__global__ __launch_bounds__(256) void kR(const float* __restrict__ f2p,
                                          const float* __restrict__ f1p,
                                          float* __restrict__ f2,
                                          float* __restrict__ f1s) {
    const int blk = blockIdx.x;
    const int tid = threadIdx.x;
    if (blk < 512) {
        const int row = blk * 4 + (tid >> 6);   // (b*256+c)
        const int t   = tid & 63;
        if (t >= 60) return;
        const float* src = f2p + (size_t)row * 3840 + t;
        float s = 0.f;
        #pragma unroll 16
        for (int k = 0; k < 64; ++k) s += src[k * 60];
        f2[(size_t)row * 60 + t] = s;
    } else {
        const int bt = blk - 512;               // b*60 + t
        const float* src = f1p + (size_t)bt * 1024 + 4 * tid;
        float4 s = make_float4(0.f,0.f,0.f,0.f);
        #pragma unroll
        for (int g = 0; g < 8; ++g) {
            const float4 v = *(const float4*)(src + (size_t)g * 480 * 1024);
            s.x += v.x; s.y += v.y; s.z += v.z; s.w += v.w;
        }
        *(float4*)(f1s + (size_t)bt * 1024 + 4 * tid) = s;
    }
}

// ---------------------------------------------------------------------------
// Kernel C (FROZEN from R3)
// ---------------------------------------------------------------------------
__global__ __launch_bounds__(256) void kC(const float* __restrict__ f1s,
                                          const float* __restrict__ w,
                                          float* __restrict__ g1) {
    const int b  = blockIdx.x / 30;
    const int tg = blockIdx.x % 30;
    const int c  = threadIdx.x;
    __shared__ float fl[2048];

    const float* rows = f1s + ((size_t)(b * 60) + tg * 2) * 1024;
    #pragma unroll
    for (int k = 0; k < 2; ++k) {
        const int idx = c + k * 256;
        *(float4*)(&fl[4 * idx]) = *(const float4*)(rows + 4 * idx);
    }
    __syncthreads();

    float a0 = 0.f, a1 = 0.f;
    #pragma unroll 4
    for (int n = 0; n < 1024; ++n) {
        const float wv = w[n * 256 + c];
        a0 += fl[n] * wv;
        a1 += fl[1024 + n] * wv;
    }
    float* dst = g1 + ((size_t)b * 60 + (size_t)(tg * 2)) * 256 + c;
    dst[0]   = a0;
    dst[256] = a1;
}

// ---------------------------------------------------------------------------
// Kernel D (FROZEN from R3)
// ---------------------------------------------------------------------------
__global__ __launch_bounds__(256) void kD(const float* __restrict__ g1,
                                          const float* __restrict__ f2,
                                          const float* __restrict__ bmat,
                                          float* __restrict__ logits) {
    const int bt = blockIdx.x;
    const int b  = bt / 60;
    const int t  = bt % 60;
    const int tid = threadIdx.x;
    const int cq = tid >> 6;
    const int s  = tid & 63;

    __shared__ float f2s[15364];
    __shared__ float g1r[256];
    __shared__ float red[256];

    const float* fsrc = f2 + (size_t)b * 15360;
    #pragma unroll
    for (int k = 0; k < 15; ++k) {
        const int idx = tid + k * 256;
        *(float4*)(&f2s[4 * idx]) = *(const float4*)(fsrc + 4 * idx);
    }
    if (tid < 64) {
        *(float4*)(&g1r[4 * tid]) = *(const float4*)(g1 + (size_t)bt * 256 + 4 * tid);
    }
    __syncthreads();

    float acc = 0.f;
    #pragma unroll 8
    for (int cc = 0; cc < 64; ++cc) {
        const int c = cq * 64 + cc;
        acc += g1r[c] * f2s[c * 60 + s];
    }
    red[tid] = acc;
    __syncthreads();
    if (tid < 60) {
        const float x = red[tid] + red[64 + tid] + red[128 + tid] + red[192 + tid]
                      + bmat[t * 60 + tid];
        logits[(size_t)bt * 60 + tid] = 1.f / (1.f + __expf(-x));
    }
}

// ---------------------------------------------------------------------------
// Kernel E (FROZEN from R3)
// ---------------------------------------------------------------------------
__global__ __launch_bounds__(256) void kE(const float* __restrict__ v,
                                          const float* __restrict__ logits,
                                          float* __restrict__ l2) {
    const int bi = blockIdx.x;
    const int b  = bi / 60;
    const int i  = bi % 60;
    const int tid = threadIdx.x;

    __shared__ float L[3600];
    const float* src = logits + (size_t)b * 3600;
    #pragma unroll
    for (int k = 0; k < 3; ++k) {
        const int idx = tid + k * 256;
        *(float4*)(&L[4 * idx]) = *(const float4*)(src + 4 * idx);
    }
    if (tid < 132) {
        const int idx = tid + 768;
        *(float4*)(&L[4 * idx]) = *(const float4*)(src + 4 * idx);
    }
    __syncthreads();

    if (tid < 60) {
        float acc = 0.f;
        #pragma unroll 4
        for (int j = 0; j < 60; ++j) acc += v[i * 60 + j] * L[j * 60 + tid];
        l2[(size_t)bi * 60 + tid] = acc;
    }
}

// ---------------------------------------------------------------------------
// Kernel F (FROZEN from R3)
// ---------------------------------------------------------------------------
__global__ __launch_bounds__(64) void kF(const float* __restrict__ l2,
                                         float* __restrict__ stats) {
    const int t = blockIdx.x;
    const int k = threadIdx.x;
    float s = 0.f, ss = 0.f;
    #pragma unroll
    for (int m = 0; m < 8; ++m) {
        const int idx = k + 64 * m;
        if (idx < 480) {
            const float x = l2[(size_t)idx * 60 + t];
            s  += x;
            ss += x * x;
        }
    }
    #pragma unroll
    for (int o = 32; o > 0; o >>= 1) { s += __shfl_xor(s, o); ss += __shfl_xor(ss, o); }
    if (k == 0) {
        const float m   = s * (1.f / 480.f);
        const float var = ss * (1.f / 480.f) - m * m;
        stats[t]      = m;
        stats[64 + t] = rsqrtf(var + 1e-5f);
    }
}

// ---------------------------------------------------------------------------
// Kernel G (FROZEN from R3)
// ---------------------------------------------------------------------------
__global__ __launch_bounds__(64) void kG(const float* __restrict__ l2,
                                         const float* __restrict__ stats,
                                         const float* __restrict__ gamma,
                                         const float* __restrict__ beta,
                                         float* __restrict__ out) {
    const int bi = blockIdx.x;
    const int i  = bi % 60;
    const int t  = threadIdx.x;

    float x = -3.0e38f;
    if (t < 60) {
        const float val = l2[(size_t)bi * 60 + t];
        const float y   = (val - stats[t]) * stats[64 + t] * gamma[t] + beta[t];
        const int  br   = (i < 36) ? (i / 12) : 3;
        const int  lo   = (br < 3) ? br * 12 : 36;
        const int  hi   = (br < 3) ? lo + 12 : 60;
        const bool valid = (t >= lo) && (t < hi);
        x = valid ? y : (y - 1e13f);
    }
    float mx = x;
    #pragma unroll
    for (int o = 32; o > 0; o >>= 1) mx = fmaxf(mx, __shfl_xor(mx, o));
    float e = 0.f;
    if (t < 60) e = __expf(x - mx);
    float sm = e;
    #pragma unroll
    for (int o = 32; o > 0; o >>= 1) sm += __shfl_xor(sm, o);
    if (t < 60) out[(size_t)bi * 60 + t] = e / sm;
}

// ---------------------------------------------------------------------------
extern "C" void kernel_launch(void* const* d_in, const int* in_sizes, int n_in,
                              void* d_out, int out_size, void* d_ws, size_t ws_size,
                              hipStream_t stream) {
    const float* seq   = (const float*)d_in[0];
    const float* w1    = (const float*)d_in[1];
    const float* w2    = (const float*)d_in[2];
    const float* w     = (const float*)d_in[3];
    const float* bmat  = (const float*)d_in[4];
    const float* v     = (const float*)d_in[5];
    const float* gamma = (const float*)d_in[6];
    const float* beta  = (const float*)d_in[7];
    float* out = (float*)d_out;
    float* ws  = (float*)d_ws;

    float* f1p    = ws;                  // 3,932,160
    float* f2p    = ws + 3932160;        // 7,864,320
    float* f2     = ws + 11796480;       //   122,880
    float* f1s    = ws + 11919360;       //   491,520
    float* g1     = ws + 12410880;       //   122,880
    float* logits = ws + 12533760;       //    28,800
    float* l2     = ws + 12562560;       //    28,800
    float* stats  = ws + 12591360;       //       128

    kA<<<1024, 256, 0, stream>>>(seq, w1, w2, f1p, f2p);
    kR<<<992, 256, 0, stream>>>(f2p, f1p, f2, f1s);
    kC<<<240, 256, 0, stream>>>(f1s, w, g1);
    kD<<<480, 256, 0, stream>>>(g1, f2, bmat, logits);
    kE<<<480, 256, 0, stream>>>(v, logits, l2);
    kF<<<60, 64, 0, stream>>>(l2, stats);
    kG<<<480, 64, 0, stream>>>(l2, stats, gamma, beta, out);
}

// Round 7
// 179.953 us; speedup vs baseline: 1.4104x; 1.0356x over previous
//
#include <hip/hip_runtime.h>
#include <cstdint>
#include <cstddef>

// B=8, C=256, N=1024, T=60
// seq [B][C][N][T] fp32 (503 MB), out [B][T][T] fp32
//
// ws layout (float offsets):
//   f1p : [8 cg][B][60][1024] partials over c-groups  -> 3,932,160  @ 0
//   f2p : [B][C][16 chunks][60] partials over n       -> 1,966,080  @ 3,932,160
//   f2  : [B][C][60]                                  ->   122,880  @ 5,898,240
//   g1  : [B][60][C]                                  ->   122,880  @ 6,021,120
//   logits: [B][60][60]                               ->    28,800  @ 6,144,000
//   l2  : [B][60][60]                                 ->    28,800  @ 6,172,800
//   stats: mean[60]@+0, rstd[60]@+64                  ->       128  @ 6,201,600

#define CSTRIDE 61440  // 1024*60 floats per c-plane

typedef float vfloat4 __attribute__((ext_vector_type(4)));

// quad-lane (xor1 + xor2) sum via DPP quad_perm — VALU only, no LDS pipe.
__device__ __forceinline__ float quad_reduce(float x) {
    int y1 = __builtin_amdgcn_update_dpp(0, __float_as_int(x), 0xB1, 0xF, 0xF, true);
    float s1 = x + __int_as_float(y1);
    int y2 = __builtin_amdgcn_update_dpp(0, __float_as_int(s1), 0x4E, 0xF, 0xF, true);
    return s1 + __int_as_float(y2);
}

// ---------------------------------------------------------------------------
// Kernel A v5: K-loop identical to R6. Flush now cross-wave-reduces the f2
// LDS buffer -> f2p shrinks 4x to [B][C][16 nc][60].
// grid 1024 = b(8) x cg(8, 32 c's) x nc(16, 64 n's); block 256.
// ---------------------------------------------------------------------------
__global__ __launch_bounds__(256) void kA(const float* __restrict__ seq,
                                          const float* __restrict__ w1,
                                          const float* __restrict__ w2,
                                          float* __restrict__ f1p,
                                          float* __restrict__ f2p) {
    const int blk  = blockIdx.x;            // 1024
    const int b    = blk >> 7;              // 0..7
    const int cg   = (blk >> 4) & 7;        // 0..7
    const int nc   = blk & 15;              // 0..15
    const int tid  = threadIdx.x;
    const int wv   = tid >> 6;              // 0..3
    const int lane = tid & 63;
    const int q    = lane & 3;              // n-sub
    const int r    = lane >> 2;             // t-quad; r==15 inactive
    const bool act = (r < 15);
    const int base_n = (nc << 6) + (wv << 4);
    const int c0   = cg << 5;

    __shared__ float lf2[7680];             // [cc 32][wv 4][60]

    float w2v[4];
    #pragma unroll
    for (int j = 0; j < 4; ++j) w2v[j] = w2[base_n + 4 * j + q];

    const size_t planeOff = (size_t)(b * 256 + c0) * CSTRIDE + (size_t)((base_n + q) * 60 + 4 * r);
    const float* p0 = seq + planeOff;
    const float* p1 = p0 + (size_t)CSTRIDE;
    const float* p2 = p0 + 2 * (size_t)CSTRIDE;
    const float* p3 = p0 + 3 * (size_t)CSTRIDE;

    vfloat4 P0[4], P1[4], P2[4], P3[4];
    #pragma unroll
    for (int j = 0; j < 4; ++j) {
        P0[j] = (vfloat4)(0.f);
        P1[j] = P0[j]; P2[j] = P0[j]; P3[j] = P0[j];
    }
    if (act) {
        #pragma unroll
        for (int j = 0; j < 4; ++j) P0[j] = __builtin_nontemporal_load((const vfloat4*)(p0 + j * 240));
        #pragma unroll
        for (int j = 0; j < 4; ++j) P1[j] = __builtin_nontemporal_load((const vfloat4*)(p1 + j * 240));
        #pragma unroll
        for (int j = 0; j < 4; ++j) P2[j] = __builtin_nontemporal_load((const vfloat4*)(p2 + j * 240));
        #pragma unroll
        for (int j = 0; j < 4; ++j) P3[j] = __builtin_nontemporal_load((const vfloat4*)(p3 + j * 240));
    }
    p0 += 4 * (size_t)CSTRIDE;
    p1 += 4 * (size_t)CSTRIDE;
    p2 += 4 * (size_t)CSTRIDE;
    p3 += 4 * (size_t)CSTRIDE;

    vfloat4 acc[4];
    #pragma unroll
    for (int j = 0; j < 4; ++j) acc[j] = (vfloat4)(0.f);

#define KA_STEP(P, S, PP)                                                               \
    {                                                                                   \
        const int cc = (ii << 2) + (S);                                                 \
        const float wc = w1[c0 + cc];                                                   \
        _Pragma("unroll")                                                               \
        for (int j = 0; j < 4; ++j) acc[j] += wc * P[j];                                \
        vfloat4 f2v = w2v[0]*P[0] + w2v[1]*P[1] + w2v[2]*P[2] + w2v[3]*P[3];            \
        if (pref) {                                                                     \
            _Pragma("unroll")                                                           \
            for (int j = 0; j < 4; ++j)                                                 \
                P[j] = __builtin_nontemporal_load((const vfloat4*)((PP) + j * 240));    \
        }                                                                               \
        f2v.x = quad_reduce(f2v.x);                                                     \
        f2v.y = quad_reduce(f2v.y);                                                     \
        f2v.z = quad_reduce(f2v.z);                                                     \
        f2v.w = quad_reduce(f2v.w);                                                     \
        if (act && q == 0) {                                                            \
            *(vfloat4*)(&lf2[(cc * 4 + wv) * 60 + 4 * r]) = f2v;                        \
        }                                                                               \
    }

    for (int ii = 0; ii < 8; ++ii) {
        const bool pref = act && (ii < 7);
        KA_STEP(P0, 0, p0)
        KA_STEP(P1, 1, p1)
        KA_STEP(P2, 2, p2)
        KA_STEP(P3, 3, p3)
        p0 += 4 * (size_t)CSTRIDE;
        p1 += 4 * (size_t)CSTRIDE;
        p2 += 4 * (size_t)CSTRIDE;
        p3 += 4 * (size_t)CSTRIDE;
    }
#undef KA_STEP

    // f1 partial write (off the pipeline's critical path)
    if (act) {
        float* dst = f1p + ((size_t)((cg * 8 + b) * 60 + 4 * r)) * 1024 + base_n + q;
        #pragma unroll
        for (int j = 0; j < 4; ++j) {
            dst[0 * 1024 + 4 * j] = acc[j].x;
            dst[1 * 1024 + 4 * j] = acc[j].y;
            dst[2 * 1024 + 4 * j] = acc[j].z;
            dst[3 * 1024 + 4 * j] = acc[j].w;
        }
    }

    // Cross-wave reduce + flush: [cc32][60] = 480 float4 per block.
    __syncthreads();
    #pragma unroll
    for (int k = 0; k < 2; ++k) {
        const int id4 = tid + k * 256;
        if (id4 < 480) {
            const int cc = id4 / 15;
            const int p  = id4 - cc * 15;
            vfloat4 s = (vfloat4)(0.f);
            #pragma unroll
            for (int w = 0; w < 4; ++w)
                s += *(const vfloat4*)(&lf2[(cc * 4 + w) * 60 + 4 * p]);
            *(vfloat4*)(f2p + ((size_t)(b * 256 + c0 + cc) * 16 + nc) * 60 + 4 * p) = s;
        }
    }
}

// ---------------------------------------------------------------------------
// Kernel R v2: f2 = sum of 16 nc chunks. grid 512 x block 256 (4 rows/block).
// ---------------------------------------------------------------------------
__global__ __launch_bounds__(256) void kR(const float* __restrict__ f2p,
                                          float* __restrict__ f2) {
    const int tid = threadIdx.x;
    const int row = blockIdx.x * 4 + (tid >> 6);   // (b*256+c)
    const int t   = tid & 63;
    if (t >= 60) return;
    const float* src = f2p + (size_t)row * 960 + t;
    float s = 0.f;
    #pragma unroll
    for (int k = 0; k < 16; ++k) s += src[k * 60];
    f2[(size_t)row * 60 + t] = s;
}

// ---------------------------------------------------------------------------
// Kernel C v3: g1[b,t,c] = sum_n f1[b,t,n]*w[n,c], summing the 8 f1p partials
// during LDS staging (f1s round-trip eliminated). grid 240 = b(8) x tg(30).
// ---------------------------------------------------------------------------
__global__ __launch_bounds__(256) void kC(const float* __restrict__ f1p,
                                          const float* __restrict__ w,
                                          float* __restrict__ g1) {
    const int b  = blockIdx.x / 30;
    const int tg = blockIdx.x % 30;
    const int c  = threadIdx.x;
    __shared__ float fl[2048];

    #pragma unroll
    for (int k = 0; k < 2; ++k) {
        const int idx  = c + k * 256;      // 0..511 float4 slots
        const int row  = idx >> 8;         // 0..1
        const int col4 = idx & 255;
        const int t    = tg * 2 + row;
        vfloat4 s = (vfloat4)(0.f);
        #pragma unroll
        for (int g = 0; g < 8; ++g)
            s += *(const vfloat4*)(f1p + ((size_t)((g * 8 + b) * 60 + t)) * 1024 + 4 * col4);
        *(vfloat4*)(&fl[row * 1024 + 4 * col4]) = s;
    }
    __syncthreads();

    float a0 = 0.f, a1 = 0.f;
    #pragma unroll 4
    for (int n = 0; n < 1024; ++n) {
        const float wv = w[n * 256 + c];
        a0 += fl[n] * wv;
        a1 += fl[1024 + n] * wv;
    }
    float* dst = g1 + ((size_t)b * 60 + (size_t)(tg * 2)) * 256 + c;
    dst[0]   = a0;
    dst[256] = a1;
}

// ---------------------------------------------------------------------------
// Kernel D (FROZEN from R3)
// ---------------------------------------------------------------------------
__global__ __launch_bounds__(256) void kD(const float* __restrict__ g1,
                                          const float* __restrict__ f2,
                                          const float* __restrict__ bmat,
                                          float* __restrict__ logits) {
    const int bt = blockIdx.x;
    const int b  = bt / 60;
    const int t  = bt % 60;
    const int tid = threadIdx.x;
    const int cq = tid >> 6;
    const int s  = tid & 63;

    __shared__ float f2s[15364];
    __shared__ float g1r[256];
    __shared__ float red[256];

    const float* fsrc = f2 + (size_t)b * 15360;
    #pragma unroll
    for (int k = 0; k < 15; ++k) {
        const int idx = tid + k * 256;
        *(float4*)(&f2s[4 * idx]) = *(const float4*)(fsrc + 4 * idx);
    }
    if (tid < 64) {
        *(float4*)(&g1r[4 * tid]) = *(const float4*)(g1 + (size_t)bt * 256 + 4 * tid);
    }
    __syncthreads();

    float acc = 0.f;
    #pragma unroll 8
    for (int cc = 0; cc < 64; ++cc) {
        const int c = cq * 64 + cc;
        acc += g1r[c] * f2s[c * 60 + s];
    }
    red[tid] = acc;
    __syncthreads();
    if (tid < 60) {
        const float x = red[tid] + red[64 + tid] + red[128 + tid] + red[192 + tid]
                      + bmat[t * 60 + tid];
        logits[(size_t)bt * 60 + tid] = 1.f / (1.f + __expf(-x));
    }
}

// ---------------------------------------------------------------------------
// Kernel E (FROZEN from R3)
// ---------------------------------------------------------------------------
__global__ __launch_bounds__(256) void kE(const float* __restrict__ v,
                                          const float* __restrict__ logits,
                                          float* __restrict__ l2) {
    const int bi = blockIdx.x;
    const int b  = bi / 60;
    const int i  = bi % 60;
    const int tid = threadIdx.x;

    __shared__ float L[3600];
    const float* src = logits + (size_t)b * 3600;
    #pragma unroll
    for (int k = 0; k < 3; ++k) {
        const int idx = tid + k * 256;
        *(float4*)(&L[4 * idx]) = *(const float4*)(src + 4 * idx);
    }
    if (tid < 132) {
        const int idx = tid + 768;
        *(float4*)(&L[4 * idx]) = *(const float4*)(src + 4 * idx);
    }
    __syncthreads();

    if (tid < 60) {
        float acc = 0.f;
        #pragma unroll 4
        for (int j = 0; j < 60; ++j) acc += v[i * 60 + j] * L[j * 60 + tid];
        l2[(size_t)bi * 60 + tid] = acc;
    }
}

// ---------------------------------------------------------------------------
// Kernel F (FROZEN from R3)
// ---------------------------------------------------------------------------
__global__ __launch_bounds__(64) void kF(const float* __restrict__ l2,
                                         float* __restrict__ stats) {
    const int t = blockIdx.x;
    const int k = threadIdx.x;
    float s = 0.f, ss = 0.f;
    #pragma unroll
    for (int m = 0; m < 8; ++m) {
        const int idx = k + 64 * m;
        if (idx < 480) {
            const float x = l2[(size_t)idx * 60 + t];
            s  += x;
            ss += x * x;
        }
    }
    #pragma unroll
    for (int o = 32; o > 0; o >>= 1) { s += __shfl_xor(s, o); ss += __shfl_xor(ss, o); }
    if (k == 0) {
        const float m   = s * (1.f / 480.f);
        const float var = ss * (1.f / 480.f) - m * m;
        stats[t]      = m;
        stats[64 + t] = rsqrtf(var + 1e-5f);
    }
}

// ---------------------------------------------------------------------------
// Kernel G (FROZEN from R3)
// ---------------------------------------------------------------------------
__global__ __launch_bounds__(64) void kG(const float* __restrict__ l2,
                                         const float* __restrict__ stats,
                                         const float* __restrict__ gamma,
                                         const float* __restrict__ beta,
                                         float* __restrict__ out) {
    const int bi = blockIdx.x;
    const int i  = bi % 60;
    const int t  = threadIdx.x;

    float x = -3.0e38f;
    if (t < 60) {
        const float val = l2[(size_t)bi * 60 + t];
        const float y   = (val - stats[t]) * stats[64 + t] * gamma[t] + beta[t];
        const int  br   = (i < 36) ? (i / 12) : 3;
        const int  lo   = (br < 3) ? br * 12 : 36;
        const int  hi   = (br < 3) ? lo + 12 : 60;
        const bool valid = (t >= lo) && (t < hi);
        x = valid ? y : (y - 1e13f);
    }
    float mx = x;
    #pragma unroll
    for (int o = 32; o > 0; o >>= 1) mx = fmaxf(mx, __shfl_xor(mx, o));
    float e = 0.f;
    if (t < 60) e = __expf(x - mx);
    float sm = e;
    #pragma unroll
    for (int o = 32; o > 0; o >>= 1) sm += __shfl_xor(sm, o);
    if (t < 60) out[(size_t)bi * 60 + t] = e / sm;
}

// ---------------------------------------------------------------------------
extern "C" void kernel_launch(void* const* d_in, const int* in_sizes, int n_in,
                              void* d_out, int out_size, void* d_ws, size_t ws_size,
                              hipStream_t stream) {
    const float* seq   = (const float*)d_in[0];
    const float* w1    = (const float*)d_in[1];
    const float* w2    = (const float*)d_in[2];
    const float* w     = (const float*)d_in[3];
    const float* bmat  = (const float*)d_in[4];
    const float* v     = (const float*)d_in[5];
    const float* gamma = (const float*)d_in[6];
    const float* beta  = (const float*)d_in[7];
    float* out = (float*)d_out;
    float* ws  = (float*)d_ws;

    float* f1p    = ws;                  // 3,932,160
    float* f2p    = ws + 3932160;        // 1,966,080
    float* f2     = ws + 5898240;        //   122,880
    float* g1     = ws + 6021120;        //   122,880
    float* logits = ws + 6144000;        //    28,800
    float* l2     = ws + 6172800;        //    28,800
    float* stats  = ws + 6201600;        //       128

    kA<<<1024, 256, 0, stream>>>(seq, w1, w2, f1p, f2p);
    kR<<<512, 256, 0, stream>>>(f2p, f2);
    kC<<<240, 256, 0, stream>>>(f1p, w, g1);
    kD<<<480, 256, 0, stream>>>(g1, f2, bmat, logits);
    kE<<<480, 256, 0, stream>>>(v, logits, l2);
    kF<<<60, 64, 0, stream>>>(l2, stats);
    kG<<<480, 64, 0, stream>>>(l2, stats, gamma, beta, out);
}